// Round 4
// baseline (3076.073 us; speedup 1.0000x reference)
//
#include <hip/hip_runtime.h>
#include <hip/hip_bf16.h>

// ---------------------------------------------------------------------------
// GAT (4 layers + fc) on MI355X. Atomic-scatter formulation.
// Runtime dtype hedging (device-side detection, graph-capture safe):
//   flags[0]: float tensors are bf16 (1) or fp32 (0)
//   flags[1]: edge_index is int64 (1) or int32 (0)
// All internal compute fp32; OUTPUT IS FP32 (reference output dtype).
// ---------------------------------------------------------------------------

__device__ __forceinline__ float bf2f(unsigned short w) {
    return __uint_as_float(((unsigned int)w) << 16);
}
__device__ __forceinline__ unsigned enc_f(float f) {
    unsigned u = __float_as_uint(f);
    return (u & 0x80000000u) ? ~u : (u | 0x80000000u);
}
__device__ __forceinline__ float dec_f(unsigned u) {
    unsigned v = (u & 0x80000000u) ? (u & 0x7FFFFFFFu) : ~u;
    return __uint_as_float(v);
}

// --------------------------- dtype detection -------------------------------
__global__ void detect_kernel(const unsigned short* __restrict__ xw,
                              const int* __restrict__ ew,
                              int* __restrict__ flags)
{
    __shared__ int cnt_sane[256];
    __shared__ int cnt_nz[256];
    const int t = threadIdx.x;
    // x as 16-bit words, even indices: bf16 reals -> sane exponent;
    // fp32 low-mantissa words -> mostly random exponent bits.
    unsigned short w = xw[2 * t];
    int e = (w >> 7) & 0xff;
    cnt_sane[t] = (e >= 110 && e <= 133) ? 1 : 0;
    // edges as 32-bit words, odd indices: int64 high words (all zero) vs
    // real int32 indices (almost never all zero).
    cnt_nz[t] = (ew[2 * t + 1] != 0) ? 1 : 0;
    __syncthreads();
    if (t == 0) {
        int s = 0, nz = 0;
        for (int i = 0; i < 256; ++i) { s += cnt_sane[i]; nz += cnt_nz[i]; }
        flags[0] = (s >= 128) ? 1 : 0;   // bf16 floats
        flags[1] = (nz == 0) ? 1 : 0;    // int64 edges
    }
}

// --------------------------- param conversion ------------------------------
struct ParamPtrs {
    const void* src[18];
    int n[18];
    int off[18];
};

__global__ void convert_params_kernel(ParamPtrs pp, const int* __restrict__ flags,
                                      float* __restrict__ out)
{
    const int b = blockIdx.x;
    const int n = pp.n[b];
    const float* fp = (const float*)pp.src[b];
    const unsigned short* hp = (const unsigned short*)pp.src[b];
    const int bf = flags[0];
    float* o = out + pp.off[b];
    for (int i = threadIdx.x; i < n; i += blockDim.x)
        o[i] = bf ? bf2f(hp[i]) : fp[i];
}

// ------------------------------- GEMM --------------------------------------
// x:[N,Fin] (fp32 ws buffer, or external w/ dtype flag) -> h:[N,Fout] fp32.
// Fused alpha_s/alpha_d. blockDim=(Fout, 256/Fout).
__global__ __launch_bounds__(256) void gemm_alpha_kernel(
    const void* __restrict__ xv, const int* __restrict__ flags, int x_ext,
    const float* __restrict__ W, const float* __restrict__ a_src,
    const float* __restrict__ a_dst, const float* __restrict__ bias,
    float* __restrict__ h,
    float* __restrict__ alpha_s, float* __restrict__ alpha_d, int has_alpha,
    int N, int Fin, int Fout, int relu_in, int has_bias)
{
    __shared__ float xs[2048];
    __shared__ float red_s[256];
    __shared__ float red_d[256];

    const int tx = threadIdx.x;
    const int ty = threadIdx.y;
    const int ROWS = blockDim.y;
    const int tid = ty * Fout + tx;
    const long long base_row = (long long)blockIdx.x * ROWS;

    const int xbf = x_ext ? flags[0] : 0;
    const float* xf = (const float*)xv;
    const unsigned short* xh = (const unsigned short*)xv;

    const int total = ROWS * Fin;
    for (int idx = tid; idx < total; idx += 256) {
        const int r = idx / Fin;
        const int c = idx - r * Fin;
        const long long grow = base_row + r;
        float v = 0.f;
        if (grow < N) {
            const long long gi = grow * Fin + c;
            v = xbf ? bf2f(xh[gi]) : xf[gi];
        }
        if (relu_in) v = fmaxf(v, 0.f);
        xs[r * Fin + c] = v;
    }
    __syncthreads();

    const long long grow = base_row + ty;
    float acc = 0.f;
    for (int k = 0; k < Fin; ++k)
        acc += xs[ty * Fin + k] * W[k * Fout + tx];
    if (has_bias) acc += bias[tx];
    if (grow < N) h[grow * Fout + tx] = acc;

    if (has_alpha) {
        red_s[tid] = acc * a_src[tx];
        red_d[tid] = acc * a_dst[tx];
        __syncthreads();
        for (int s = Fout >> 1; s > 0; s >>= 1) {
            if (tx < s) {
                red_s[tid] += red_s[tid + s];
                red_d[tid] += red_d[tid + s];
            }
            __syncthreads();
        }
        if (tx == 0 && grow < N) {
            alpha_s[grow] = red_s[ty * Fout];
            alpha_d[grow] = red_d[ty * Fout];
        }
    }
}

// ----------------------------- edge helpers --------------------------------
__device__ __forceinline__ void edge_sd(const int* __restrict__ e, long long t,
                                        long long E, int e64, int& s, int& d)
{
    if (t >= E) { s = (int)(t - E); d = s; return; }
    if (e64) { s = e[2 * t]; d = e[2 * E + 2 * t]; }
    else     { s = e[t];     d = e[E + t]; }
}

// out = bias broadcast; maxenc = 0 (== -NaN under enc); denom = 0
__global__ void init_layer_kernel(float* __restrict__ out, const float* __restrict__ b,
                                  unsigned* __restrict__ maxenc, float* __restrict__ denom,
                                  long long NF, int FoutMask, int N)
{
    long long idx = (long long)blockIdx.x * blockDim.x + threadIdx.x;
    if (idx < NF) out[idx] = b[(int)(idx & FoutMask)];
    if (idx < N) { maxenc[idx] = 0u; denom[idx] = 0.f; }
}

__global__ void edge_max_kernel(const int* __restrict__ e, const int* __restrict__ flags,
                                const float* __restrict__ as, const float* __restrict__ ad,
                                unsigned* __restrict__ maxenc, long long E, long long Et)
{
    long long t = (long long)blockIdx.x * blockDim.x + threadIdx.x;
    if (t >= Et) return;
    int s, d; edge_sd(e, t, E, flags[1], s, d);
    float v = as[s] + ad[d];
    v = (v > 0.f) ? v : 0.2f * v;
    atomicMax(&maxenc[d], enc_f(v));
}

__global__ void edge_expsum_kernel(const int* __restrict__ e, const int* __restrict__ flags,
                                   const float* __restrict__ as, const float* __restrict__ ad,
                                   const unsigned* __restrict__ maxenc,
                                   float* __restrict__ denom, long long E, long long Et)
{
    long long t = (long long)blockIdx.x * blockDim.x + threadIdx.x;
    if (t >= Et) return;
    int s, d; edge_sd(e, t, E, flags[1], s, d);
    float v = as[s] + ad[d];
    v = (v > 0.f) ? v : 0.2f * v;
    atomicAdd(&denom[d], expf(v - dec_f(maxenc[d])));
}

// blockDim = (Fout, 256/Fout): one edge per y-slice, coalesced feature atomics
__global__ __launch_bounds__(256) void edge_scatter_kernel(
    const int* __restrict__ e, const int* __restrict__ flags,
    const float* __restrict__ as, const float* __restrict__ ad,
    const unsigned* __restrict__ maxenc, const float* __restrict__ denom,
    const float* __restrict__ h, float* __restrict__ out,
    long long E, long long Et, int Fout)
{
    const int epb = blockDim.y;
    const long long t = (long long)blockIdx.x * epb + threadIdx.y;
    if (t >= Et) return;
    int s, d; edge_sd(e, t, E, flags[1], s, d);
    float v = as[s] + ad[d];
    v = (v > 0.f) ? v : 0.2f * v;
    const float w = expf(v - dec_f(maxenc[d])) / denom[d];
    const int j = threadIdx.x;
    atomicAdd(&out[(long long)d * Fout + j], h[(long long)s * Fout + j] * w);
}

// ------------------------------- launch ------------------------------------
extern "C" void kernel_launch(void* const* d_in, const int* in_sizes, int n_in,
                              void* d_out, int out_size, void* d_ws, size_t ws_size,
                              hipStream_t stream)
{
    const int INP = 128;
    const int N = in_sizes[0] / INP;                 // 50000
    const long long E = in_sizes[1] / 2;             // 1600000
    const long long Et = E + N;

    const int Fin[4]  = {128, 32, 64, 128};
    const int Fout[4] = {32, 64, 128, 128};

    // ---- workspace layout (~53 MB) ----
    char* p = (char*)d_ws;
    auto alloc = [&](size_t bytes) {
        char* r = p;
        p += (bytes + 255) & ~(size_t)255;
        return r;
    };
    float*    bufH   = (float*)   alloc((size_t)N * 128 * sizeof(float));
    float*    bufX   = (float*)   alloc((size_t)N * 128 * sizeof(float));
    float*    as     = (float*)   alloc((size_t)N * sizeof(float));
    float*    ad     = (float*)   alloc((size_t)N * sizeof(float));
    unsigned* maxenc = (unsigned*)alloc((size_t)N * sizeof(unsigned));
    float*    denom  = (float*)   alloc((size_t)N * sizeof(float));
    int*      flags  = (int*)     alloc(64);
    float*    params = (float*)   alloc(64 * 1024 * sizeof(float));
    (void)ws_size;

    // ---- dtype detection ----
    detect_kernel<<<1, 256, 0, stream>>>((const unsigned short*)d_in[0],
                                         (const int*)d_in[1], flags);

    // ---- param conversion into fp32 block ----
    ParamPtrs pp;
    int off = 0;
    int sizes[18];
    {
        int k = 0;
        for (int i = 0; i < 4; ++i) {
            sizes[k++] = Fin[i] * Fout[i];   // W
            sizes[k++] = Fout[i];            // a_src
            sizes[k++] = Fout[i];            // a_dst
            sizes[k++] = Fout[i];            // b
        }
        sizes[16] = 128 * 16;                // fc_W
        sizes[17] = 16;                      // fc_b
        for (int i = 0; i < 18; ++i) {
            pp.src[i] = d_in[2 + i];
            pp.n[i] = sizes[i];
            pp.off[i] = off;
            off += sizes[i];
        }
    }
    convert_params_kernel<<<18, 256, 0, stream>>>(pp, flags, params);

    const float* Wl[4], *asr[4], *adt[4], *bl[4];
    for (int i = 0; i < 4; ++i) {
        Wl[i]  = params + pp.off[4 * i + 0];
        asr[i] = params + pp.off[4 * i + 1];
        adt[i] = params + pp.off[4 * i + 2];
        bl[i]  = params + pp.off[4 * i + 3];
    }
    const float* fcW = params + pp.off[16];
    const float* fcb = params + pp.off[17];

    const int* e32 = (const int*)d_in[1];

    const void* xin = d_in[0];
    int x_ext = 1;
    for (int i = 0; i < 4; ++i) {
        const int fin = Fin[i], fout = Fout[i];
        const int rows = 256 / fout;
        dim3 gb(fout, rows);
        int ggrid = (N + rows - 1) / rows;
        gemm_alpha_kernel<<<ggrid, gb, 0, stream>>>(
            xin, flags, x_ext, Wl[i], asr[i], adt[i], nullptr,
            bufH, as, ad, 1,
            N, fin, fout, i > 0 ? 1 : 0, 0);

        const long long NF = (long long)N * fout;
        int iblocks = (int)((NF + 255) / 256);
        init_layer_kernel<<<iblocks, 256, 0, stream>>>(bufX, bl[i], maxenc, denom,
                                                       NF, fout - 1, N);

        int eblocks = (int)((Et + 255) / 256);
        edge_max_kernel<<<eblocks, 256, 0, stream>>>(e32, flags, as, ad, maxenc, E, Et);
        edge_expsum_kernel<<<eblocks, 256, 0, stream>>>(e32, flags, as, ad, maxenc,
                                                        denom, E, Et);

        dim3 sb(fout, rows);
        int sblocks = (int)((Et + rows - 1) / rows);
        edge_scatter_kernel<<<sblocks, sb, 0, stream>>>(e32, flags, as, ad, maxenc,
                                                        denom, bufH, bufX, E, Et, fout);
        xin = bufX;
        x_ext = 0;
    }

    // final fc: out = relu(x) @ fc_W + fc_b  (Fout=16), FP32 output
    {
        dim3 gb(16, 16);
        int ggrid = (N + 15) / 16;
        gemm_alpha_kernel<<<ggrid, gb, 0, stream>>>(
            xin, flags, 0, fcW, nullptr, nullptr, fcb,
            (float*)d_out, nullptr, nullptr, 0,
            N, 128, 16, 1, 1);
    }
}

// Round 5
// 1124.259 us; speedup vs baseline: 2.7361x; 2.7361x over previous
//
#include <hip/hip_runtime.h>
#include <hip/hip_bf16.h>

// ---------------------------------------------------------------------------
// GAT (4 layers + fc) on MI355X. CSR-gather formulation (no float atomics).
// Runtime dtype hedging (device-side detection, graph-capture safe):
//   flags[0]: float tensors are bf16 (1) or fp32 (0)
//   flags[1]: edge_index is int64 (1) or int32 (0)
// All internal compute fp32; output fp32.
// Per layer: gemm(+alpha dots) -> wave-per-dst gather (softmax + weighted sum).
// ---------------------------------------------------------------------------

__device__ __forceinline__ float bf2f(unsigned short w) {
    return __uint_as_float(((unsigned int)w) << 16);
}

// --------------------------- dtype detection -------------------------------
__global__ void detect_kernel(const unsigned short* __restrict__ xw,
                              const int* __restrict__ ew,
                              int* __restrict__ flags)
{
    __shared__ int cnt_sane[256];
    __shared__ int cnt_nz[256];
    const int t = threadIdx.x;
    unsigned short w = xw[2 * t];
    int e = (w >> 7) & 0xff;
    cnt_sane[t] = (e >= 110 && e <= 133) ? 1 : 0;
    cnt_nz[t] = (ew[2 * t + 1] != 0) ? 1 : 0;
    __syncthreads();
    if (t == 0) {
        int s = 0, nz = 0;
        for (int i = 0; i < 256; ++i) { s += cnt_sane[i]; nz += cnt_nz[i]; }
        flags[0] = (s >= 128) ? 1 : 0;   // bf16 floats
        flags[1] = (nz == 0) ? 1 : 0;    // int64 edges
    }
}

// --------------------------- param conversion ------------------------------
struct ParamPtrs {
    const void* src[18];
    int n[18];
    int off[18];
};

__global__ void convert_params_kernel(ParamPtrs pp, const int* __restrict__ flags,
                                      float* __restrict__ out)
{
    const int b = blockIdx.x;
    const int n = pp.n[b];
    const float* fp = (const float*)pp.src[b];
    const unsigned short* hp = (const unsigned short*)pp.src[b];
    const int bf = flags[0];
    float* o = out + pp.off[b];
    for (int i = threadIdx.x; i < n; i += blockDim.x)
        o[i] = bf ? bf2f(hp[i]) : fp[i];
}

// ----------------------------- edge helpers --------------------------------
__device__ __forceinline__ void edge_sd(const int* __restrict__ e, long long t,
                                        long long E, int e64, int& s, int& d)
{
    if (t >= E) { s = (int)(t - E); d = s; return; }
    if (e64) { s = e[2 * t]; d = e[2 * E + 2 * t]; }
    else     { s = e[t];     d = e[E + t]; }
}

// ------------------------------ CSR build ----------------------------------
__global__ void zero_int_kernel(int* __restrict__ p, int n)
{
    int i = blockIdx.x * blockDim.x + threadIdx.x;
    if (i < n) p[i] = 0;
}

__global__ void csr_count_kernel(const int* __restrict__ e, const int* __restrict__ flags,
                                 int* __restrict__ deg, long long E, long long Et)
{
    long long t = (long long)blockIdx.x * blockDim.x + threadIdx.x;
    if (t >= Et) return;
    int s, d; edge_sd(e, t, E, flags[1], s, d);
    atomicAdd(&deg[d], 1);
}

// single block, 256 threads: exclusive scan of deg -> rowptr, fillpos
__global__ void csr_scan_kernel(const int* __restrict__ deg, int* __restrict__ rowptr,
                                int* __restrict__ fillpos, int N)
{
    __shared__ int sums[256];
    const int t = threadIdx.x;
    const int chunk = (N + 255) / 256;
    const int lo = t * chunk;
    const int hi = min(N, lo + chunk);
    int s = 0;
    for (int i = lo; i < hi; ++i) s += deg[i];
    sums[t] = s;
    __syncthreads();
    if (t == 0) {
        int a = 0;
        for (int i = 0; i < 256; ++i) { int v = sums[i]; sums[i] = a; a += v; }
        rowptr[N] = a;
    }
    __syncthreads();
    int a = sums[t];
    for (int i = lo; i < hi; ++i) {
        rowptr[i] = a;
        fillpos[i] = a;
        a += deg[i];
    }
}

__global__ void csr_fill_kernel(const int* __restrict__ e, const int* __restrict__ flags,
                                int* __restrict__ fillpos, int* __restrict__ csr_src,
                                long long E, long long Et)
{
    long long t = (long long)blockIdx.x * blockDim.x + threadIdx.x;
    if (t >= Et) return;
    int s, d; edge_sd(e, t, E, flags[1], s, d);
    int pos = atomicAdd(&fillpos[d], 1);
    csr_src[pos] = s;
}

// ------------------------------- GEMM --------------------------------------
// x:[N,Fin] -> h:[N,Fout] fp32, fused alpha dots. blockDim=(Fout, 256/Fout).
__global__ __launch_bounds__(256) void gemm_alpha_kernel(
    const void* __restrict__ xv, const int* __restrict__ flags, int x_ext,
    const float* __restrict__ W, const float* __restrict__ a_src,
    const float* __restrict__ a_dst, const float* __restrict__ bias,
    float* __restrict__ h,
    float* __restrict__ alpha_s, float* __restrict__ alpha_d, int has_alpha,
    int N, int Fin, int Fout, int relu_in, int has_bias)
{
    __shared__ float xs[2048];
    __shared__ float red_s[256];
    __shared__ float red_d[256];

    const int tx = threadIdx.x;
    const int ty = threadIdx.y;
    const int ROWS = blockDim.y;
    const int tid = ty * Fout + tx;
    const long long base_row = (long long)blockIdx.x * ROWS;

    const int xbf = x_ext ? flags[0] : 0;
    const float* xf = (const float*)xv;
    const unsigned short* xh = (const unsigned short*)xv;

    const int total = ROWS * Fin;
    for (int idx = tid; idx < total; idx += 256) {
        const int r = idx / Fin;
        const int c = idx - r * Fin;
        const long long grow = base_row + r;
        float v = 0.f;
        if (grow < N) {
            const long long gi = grow * Fin + c;
            v = xbf ? bf2f(xh[gi]) : xf[gi];
        }
        if (relu_in) v = fmaxf(v, 0.f);
        xs[r * Fin + c] = v;
    }
    __syncthreads();

    const long long grow = base_row + ty;
    float acc = 0.f;
    for (int k = 0; k < Fin; ++k)
        acc += xs[ty * Fin + k] * W[k * Fout + tx];
    if (has_bias) acc += bias[tx];
    if (grow < N) h[grow * Fout + tx] = acc;

    if (has_alpha) {
        red_s[tid] = acc * a_src[tx];
        red_d[tid] = acc * a_dst[tx];
        __syncthreads();
        for (int s = Fout >> 1; s > 0; s >>= 1) {
            if (tx < s) {
                red_s[tid] += red_s[tid + s];
                red_d[tid] += red_d[tid + s];
            }
            __syncthreads();
        }
        if (tx == 0 && grow < N) {
            alpha_s[grow] = red_s[ty * Fout];
            alpha_d[grow] = red_d[ty * Fout];
        }
    }
}

// --------------------------- gather (per-dst wave) -------------------------
// One wave per destination node. Softmax over incoming edges + weighted sum
// of h[src] rows, all in registers (shfl broadcast). out = bias + sum/den.
// Fout in {32, 64, 128}.
__global__ __launch_bounds__(256) void gat_gather_kernel(
    const int* __restrict__ rowptr, const int* __restrict__ csr_src,
    const float* __restrict__ as, const float* __restrict__ ad,
    const float* __restrict__ h, const float* __restrict__ bias,
    float* __restrict__ out, int N, int Fout)
{
    const int wslot = threadIdx.x >> 6;
    const int lane = threadIdx.x & 63;
    const int d = blockIdx.x * 4 + wslot;
    if (d >= N) return;

    const int r0 = rowptr[d];
    const int r1 = rowptr[d + 1];
    const float add = ad[d];

    // pass 1: segment max
    float m = -INFINITY;
    for (int base = r0; base < r1; base += 64) {
        const int e = base + lane;
        if (e < r1) {
            const int s = csr_src[e];
            float v = as[s] + add;
            v = (v > 0.f) ? v : 0.2f * v;
            m = fmaxf(m, v);
        }
    }
    for (int off = 32; off > 0; off >>= 1)
        m = fmaxf(m, __shfl_down(m, off, 64));
    m = __shfl(m, 0, 64);

    // pass 2: exp weights + feature accumulation
    const int sub = (Fout < 64) ? (lane / Fout) : 0;   // edge sub-slot
    const int f   = (Fout < 64) ? (lane % Fout) : lane;
    const int epi = (Fout < 64) ? (64 / Fout) : 1;     // edges per inner iter

    float den = 0.f;
    float acc0 = 0.f, acc1 = 0.f;
    for (int base = r0; base < r1; base += 64) {
        const int e = base + lane;
        float p = 0.f;
        int s = 0;
        if (e < r1) {
            s = csr_src[e];
            float v = as[s] + add;
            v = (v > 0.f) ? v : 0.2f * v;
            p = expf(v - m);
        }
        den += p;
        const int cnt = min(64, r1 - base);
        for (int j = 0; j < cnt; j += epi) {
            const float pj = __shfl(p, j + sub, 64);   // 0 for OOB slot
            const int   sj = __shfl(s, j + sub, 64);
            acc0 += pj * h[sj * Fout + f];
            if (Fout == 128) acc1 += pj * h[sj * Fout + f + 64];
        }
    }
    // total denominator across the wave
    for (int off = 32; off > 0; off >>= 1)
        den += __shfl_down(den, off, 64);
    den = __shfl(den, 0, 64);
    const float inv = 1.f / den;

    if (Fout == 128) {
        out[(long long)d * 128 + lane]      = bias[lane] + acc0 * inv;
        out[(long long)d * 128 + lane + 64] = bias[lane + 64] + acc1 * inv;
    } else if (Fout == 64) {
        out[(long long)d * 64 + lane] = bias[lane] + acc0 * inv;
    } else { // 32: combine the two edge sub-slot partials
        acc0 += __shfl_down(acc0, 32, 64);
        if (lane < 32)
            out[(long long)d * 32 + lane] = bias[lane] + acc0 * inv;
    }
}

// ------------------------------- launch ------------------------------------
extern "C" void kernel_launch(void* const* d_in, const int* in_sizes, int n_in,
                              void* d_out, int out_size, void* d_ws, size_t ws_size,
                              hipStream_t stream)
{
    const int INP = 128;
    const int N = in_sizes[0] / INP;                 // 50000
    const long long E = in_sizes[1] / 2;             // 1600000
    const long long Et = E + N;

    const int Fin[4]  = {128, 32, 64, 128};
    const int Fout[4] = {32, 64, 128, 128};

    // ---- workspace layout (~59 MB) ----
    char* p = (char*)d_ws;
    auto alloc = [&](size_t bytes) {
        char* r = p;
        p += (bytes + 255) & ~(size_t)255;
        return r;
    };
    float* bufH    = (float*)alloc((size_t)N * 128 * sizeof(float));
    float* bufX    = (float*)alloc((size_t)N * 128 * sizeof(float));
    float* as      = (float*)alloc((size_t)N * sizeof(float));
    float* ad      = (float*)alloc((size_t)N * sizeof(float));
    int*   deg     = (int*)  alloc((size_t)N * sizeof(int));
    int*   rowptr  = (int*)  alloc((size_t)(N + 1) * sizeof(int));
    int*   fillpos = (int*)  alloc((size_t)N * sizeof(int));
    int*   csr_src = (int*)  alloc((size_t)Et * sizeof(int));
    int*   flags   = (int*)  alloc(64);
    float* params  = (float*)alloc(64 * 1024 * sizeof(float));
    (void)ws_size;

    // ---- dtype detection ----
    detect_kernel<<<1, 256, 0, stream>>>((const unsigned short*)d_in[0],
                                         (const int*)d_in[1], flags);

    // ---- param conversion into fp32 block ----
    ParamPtrs pp;
    int off = 0;
    int sizes[18];
    {
        int k = 0;
        for (int i = 0; i < 4; ++i) {
            sizes[k++] = Fin[i] * Fout[i];
            sizes[k++] = Fout[i];
            sizes[k++] = Fout[i];
            sizes[k++] = Fout[i];
        }
        sizes[16] = 128 * 16;
        sizes[17] = 16;
        for (int i = 0; i < 18; ++i) {
            pp.src[i] = d_in[2 + i];
            pp.n[i] = sizes[i];
            pp.off[i] = off;
            off += sizes[i];
        }
    }
    convert_params_kernel<<<18, 256, 0, stream>>>(pp, flags, params);

    const float* Wl[4], *asr[4], *adt[4], *bl[4];
    for (int i = 0; i < 4; ++i) {
        Wl[i]  = params + pp.off[4 * i + 0];
        asr[i] = params + pp.off[4 * i + 1];
        adt[i] = params + pp.off[4 * i + 2];
        bl[i]  = params + pp.off[4 * i + 3];
    }
    const float* fcW = params + pp.off[16];
    const float* fcb = params + pp.off[17];

    const int* e32 = (const int*)d_in[1];

    // ---- CSR build (by destination), once per call ----
    {
        int zblocks = (N + 255) / 256;
        zero_int_kernel<<<zblocks, 256, 0, stream>>>(deg, N);
        int eblocks = (int)((Et + 255) / 256);
        csr_count_kernel<<<eblocks, 256, 0, stream>>>(e32, flags, deg, E, Et);
        csr_scan_kernel<<<1, 256, 0, stream>>>(deg, rowptr, fillpos, N);
        csr_fill_kernel<<<eblocks, 256, 0, stream>>>(e32, flags, fillpos, csr_src, E, Et);
    }

    // ---- layers ----
    const void* xin = d_in[0];
    int x_ext = 1;
    for (int i = 0; i < 4; ++i) {
        const int fin = Fin[i], fout = Fout[i];
        const int rows = 256 / fout;
        dim3 gb(fout, rows);
        int ggrid = (N + rows - 1) / rows;
        gemm_alpha_kernel<<<ggrid, gb, 0, stream>>>(
            xin, flags, x_ext, Wl[i], asr[i], adt[i], nullptr,
            bufH, as, ad, 1,
            N, fin, fout, i > 0 ? 1 : 0, 0);

        int gblocks = (N + 3) / 4;   // 4 waves per block, 1 wave per dst node
        gat_gather_kernel<<<gblocks, 256, 0, stream>>>(
            rowptr, csr_src, as, ad, bufH, bl[i], bufX, N, fout);

        xin = bufX;
        x_ext = 0;
    }

    // final fc: out = relu(x) @ fc_W + fc_b  (Fout=16), fp32 output
    {
        dim3 gb(16, 16);
        int ggrid = (N + 15) / 16;
        gemm_alpha_kernel<<<ggrid, gb, 0, stream>>>(
            xin, flags, 0, fcW, nullptr, nullptr, fcb,
            (float*)d_out, nullptr, nullptr, 0,
            N, 128, 16, 1, 1);
    }
}